// Round 14
// baseline (115.920 us; speedup 1.0000x reference)
//
#include <hip/hip_runtime.h>
#include <math.h>

#define HW 48
#define NPIX 2304          // 48*48
#define CF 64
#define CQ 32
#define RAD 12
#define PP 25
#define NTAP 625           // 25*25
#define KTOP 20
#define DILINT 16
#define QW 192
#define CSTRIDE 640        // corr row stride (625 padded)
#define NPB 6              // pixels per corr_band block
#define NC 30              // staged columns per row (j+dx: 0..29)
#define LROW 68            // LDS col stride in floats
#define DGS 28             // dgrid row stride

// ---- helpers ---------------------------------------------------------------

// ref_index may arrive as int32 or int64; detect via first 8 bytes.
__device__ inline int read_ref_index(const void* rip, int r) {
    const long long* p64 = (const long long*)rip;
    long long v0 = p64[0];
    if (v0 >= 0 && v0 < 1000000) return (int)p64[r];   // plausible int64 layout
    return ((const int*)rip)[r];                       // int32 layout
}

__device__ inline int get_dil(const void* refIdx, const void* curInd, int r,
                              bool* isLong) {
    int cur = ((const int*)curInd)[0];
    int gap = cur - read_ref_index(refIdx, r);
    *isLong = gap > DILINT;
    return *isLong ? min(4, gap / DILINT + 1) : 1;
}

// bilinear (long) / integer (short) color gather for tap id at pixel (y,x)
__device__ inline float gather_color(const float* __restrict__ qb, int c,
                                     int y, int x, int id, bool isLong,
                                     float oy, float ox) {
    int dr = id / PP - RAD, dc = id % PP - RAD;
    float img = 0.f;
    if (isLong) {
        float py = (float)y + oy + (float)dr;
        float px = (float)x + ox + (float)dc;
        float fy0 = floorf(py), fx0 = floorf(px);
        int y0 = (int)fy0, x0 = (int)fx0;
        float wy = py - fy0, wx = px - fx0;
        float w00 = (1.f - wy) * (1.f - wx), w01 = (1.f - wy) * wx;
        float w10 = wy * (1.f - wx), w11 = wy * wx;
        if (y0 >= 0 && y0 < HW && x0 >= 0 && x0 < HW)
            img += w00 * qb[(y0 * HW + x0) * CQ + c];
        if (y0 >= 0 && y0 < HW && x0 + 1 >= 0 && x0 + 1 < HW)
            img += w01 * qb[(y0 * HW + x0 + 1) * CQ + c];
        if (y0 + 1 >= 0 && y0 + 1 < HW && x0 >= 0 && x0 < HW)
            img += w10 * qb[((y0 + 1) * HW + x0) * CQ + c];
        if (y0 + 1 >= 0 && y0 + 1 < HW && x0 + 1 >= 0 && x0 + 1 < HW)
            img += w11 * qb[((y0 + 1) * HW + x0 + 1) * CQ + c];
    } else {
        int yy = y + dr, xx = x + dc;
        if (yy >= 0 && yy < HW && xx >= 0 && xx < HW)
            img = qb[(yy * HW + xx) * CQ + c];
    }
    return img;
}

// ---- kernel 1: layout prep (R11 proven form) -------------------------------
__global__ void prep_kernel(const float* __restrict__ fr,
                            const float* __restrict__ ft,
                            const float* __restrict__ q, int nref,
                            float* __restrict__ ftT,
                            float* __restrict__ frT,
                            float* __restrict__ qrT) {
    int i = blockIdx.x * blockDim.x + threadIdx.x;
    int tft = NPIX * CF;
    int tfr = nref * NPIX * CF;
    int tqr = nref * NPIX * CQ;
    if (i < tft) {
        int p = i >> 6, c = i & 63;
        ftT[i] = ft[c * NPIX + p];
    } else if (i < tft + tfr) {
        int j = i - tft;
        int rr = j / (NPIX * CF);
        int rem = j % (NPIX * CF);
        int p = rem >> 6, c = rem & 63;
        frT[j] = fr[((size_t)rr * CF + c) * NPIX + p];
    } else if (i < tft + tfr + tqr) {
        int j = i - tft - tfr;
        int rr = j / (NPIX * CQ);
        int rem = j % (NPIX * CQ);
        int p = rem >> 5, c = rem & 31;
        int y = p / HW, x = p % HW;
        qrT[j] = q[(((size_t)rr * CQ + c) * QW + 4 * y) * QW + 4 * x];
    }
}

// ---- kernel 2a: integer-tap correlation, column-ownership register blocking
// Thread (c,e): c = staged column 0..29, e = 8-channel slice 0..7.
// Per row: read 32B of LDS ONCE, 6 partial dots vs register ft slices,
// 3-level shfl reduce over e, lane e stores tap (pixel j=e, dx=c-e).
__global__ __launch_bounds__(256) void corr_band(
    const float* __restrict__ ftT, const float* __restrict__ frT,
    const void* __restrict__ refIdx, const void* __restrict__ curInd,
    float* __restrict__ corr) {
    __shared__ float lrow[NC * LROW];

    int tid = threadIdx.x;
    int bx = blockIdx.x % 9;
    int y = blockIdx.x / 9;
    int r = blockIdx.y;

    bool isLong;
    int dil = get_dil(refIdx, curInd, r, &isLong);
    int nb = (dil == 3) ? 9 : 8;
    if (bx >= nb) return;

    int m = bx % dil, grp = bx / dil;
    int npr = HW / dil;

    int c = tid >> 3;                  // column 0..31 (use <30)
    int e = tid & 7;                   // 8-channel slice
    bool cact = (c < NC);

    // ft slices for the block's 6 pixels (8 ch each) + validity
    float4 fta[NPB][2];
    bool jv[NPB];
    int pjr[NPB];
#pragma unroll
    for (int j = 0; j < NPB; ++j) {
        int xoff = grp * NPB + j;
        jv[j] = (xoff < npr);
        int xj = m + dil * xoff;
        pjr[j] = y * HW + (jv[j] ? xj : 0);
        const float4* fp = (const float4*)(ftT + (size_t)pjr[j] * CF + e * 8);
        fta[j][0] = fp[0];
        fta[j][1] = fp[1];
    }

    // this lane's store tap: pixel j=e, dx=c-e
    int dxs = c - e;
    bool st_ok = cact && (e < NPB) && (dxs >= 0) && (dxs < PP);
    int pj_e = 0; bool jv_e = false;
#pragma unroll
    for (int j = 0; j < NPB; ++j)
        if (e == j) { pj_e = pjr[j]; jv_e = jv[j]; }
    st_ok = st_ok && jv_e;
    float* outp = corr + ((size_t)r * NPIX + pj_e) * CSTRIDE + dxs;

    const float* frb = frT + (size_t)r * NPIX * CF;
    int gc0 = m + dil * (grp * NPB - RAD);

    for (int dy = 0; dy < PP; ++dy) {
        int yy = y + dil * (dy - RAD);
        if (yy < 0 || yy >= HW) {              // block-uniform
            if (st_ok) outp[dy * PP] = 0.f;
            continue;
        }
        // stage 30 cols x 64 ch (480 16B chunks over 256 threads)
        for (int k = tid; k < NC * 16; k += 256) {
            int col = k >> 4, sub = k & 15;
            int gc = gc0 + dil * col;
            float4 v = {0.f, 0.f, 0.f, 0.f};
            if (gc >= 0 && gc < HW)
                v = *(const float4*)(frb + ((size_t)yy * HW + gc) * CF + sub * 4);
            *(float4*)(lrow + col * LROW + sub * 4) = v;
        }
        __syncthreads();

        // read own column slice once, 6 partial dots
        const float* bp = lrow + c * LROW + e * 8;
        float4 b0 = *(const float4*)(bp);
        float4 b1 = *(const float4*)(bp + 4);
        float part[NPB];
#pragma unroll
        for (int j = 0; j < NPB; ++j) {
            part[j] = fta[j][0].x * b0.x + fta[j][0].y * b0.y +
                      fta[j][0].z * b0.z + fta[j][0].w * b0.w +
                      fta[j][1].x * b1.x + fta[j][1].y * b1.y +
                      fta[j][1].z * b1.z + fta[j][1].w * b1.w;
        }
        // reduce over the 8 e-lanes (contiguous in wave)
#pragma unroll
        for (int s = 1; s < 8; s <<= 1) {
#pragma unroll
            for (int j = 0; j < NPB; ++j)
                part[j] += __shfl_xor(part[j], s, 64);
        }
        // lane e stores tap (pixel e, dx=c-e)
        float sv = part[0];
#pragma unroll
        for (int j = 1; j < NPB; ++j)
            if (e == j) sv = part[j];
        if (st_ok) outp[dy * PP] = sv;
        __syncthreads();
    }
}

// ---- kernel 2b: fused per-pixel block, one wave per ref (R13 form) ---------
__global__ __launch_bounds__(192) void corr_fuse(
    const float* __restrict__ ftT, const float* __restrict__ frT,
    const float* __restrict__ qrT, const float* __restrict__ corr,
    const void* __restrict__ refIdx, const void* __restrict__ curInd,
    int nref, float* __restrict__ out) {
    __shared__ float dgw_s[3][27 * DGS];
    __shared__ float accL[3][64];
    __shared__ float ssmL[3][64];
    __shared__ float offL[3][2];
    __shared__ float mL[3];

    int tid = threadIdx.x;
    int wid = tid >> 6, lane = tid & 63;
    int p = blockIdx.x;
    int y = p / HW, x = p % HW;
    int r = wid;                      // one wave per ref (block = 64*nref)

    bool isLong;
    int dil = get_dil(refIdx, curInd, r, &isLong);
    float oy = 0.f, ox = 0.f;

    const float* cb = corr + ((size_t)r * NPIX + p) * CSTRIDE;
    float creg[10];
#pragma unroll
    for (int jj = 0; jj < 10; ++jj) {
        int t = lane + 64 * jj;
        creg[jj] = (t < NTAP) ? cb[t] : -INFINITY;
    }

    if (isLong) {
        // softmax over 625 taps -> expected offsets (exact expf: feeds top-k)
        float M = -INFINITY;
#pragma unroll
        for (int jj = 0; jj < 10; ++jj) M = fmaxf(M, creg[jj]);
#pragma unroll
        for (int s = 32; s; s >>= 1) M = fmaxf(M, __shfl_xor(M, s, 64));
        float s0 = 0.f, sy = 0.f, sx = 0.f;
#pragma unroll
        for (int jj = 0; jj < 10; ++jj) {
            int t = lane + 64 * jj;
            if (t < NTAP) {
                float e = expf(creg[jj] - M);
                int dy = t / PP - RAD, dx = t % PP - RAD;
                s0 += e; sy += e * (float)dy; sx += e * (float)dx;
            }
        }
#pragma unroll
        for (int s = 32; s; s >>= 1) {
            s0 += __shfl_xor(s0, s, 64);
            sy += __shfl_xor(sy, s, 64);
            sx += __shfl_xor(sx, s, 64);
        }
        oy = sy / s0 * (float)dil;
        ox = sx / s0 * (float)dil;
        if (lane == 0) { offL[r][0] = oy; offL[r][1] = ox; }
    }
    __syncthreads();

    // Phase B: cooperative corner grids (all threads, each long ref)
    for (int rr = 0; rr < nref; ++rr) {
        bool rrLong;
        get_dil(refIdx, curInd, rr, &rrLong);
        if (!rrLong) continue;                  // block-uniform
        float roy = offL[rr][0], rox = offL[rr][1];
        float fy = (float)y + roy, fx = (float)x + rox;
        int iy0 = (int)floorf(fy), ix0 = (int)floorf(fx);

        int cs = tid & 15;
        int g2 = tid >> 4;                      // 0..11 coop-16 groups
        float4 fqc = ((const float4*)(ftT + (size_t)p * CF))[cs];
        const float* frb = frT + (size_t)rr * NPIX * CF;
        float* dgw = dgw_s[rr];
        int colbase = ix0 - RAD;
        for (int a = 0; a < 26; ++a) {
            int yy = iy0 - RAD + a;
            bool yok = (yy >= 0 && yy < HW);
            const float* rowp = frb + (size_t)(yok ? yy : 0) * (HW * CF);
#pragma unroll
            for (int i = 0; i < 3; ++i) {
                int lc2 = 12 * i + g2;          // 0..35, use <26
                int xx2 = colbase + lc2;
                int xs = min(max(xx2, 0), HW - 1);
                float s = 0.f;
                if (yok && lc2 < 26) {
                    float4 b = *(const float4*)(rowp + xs * CF + 4 * cs);
                    s = fqc.x * b.x + fqc.y * b.y + fqc.z * b.z + fqc.w * b.w;
                    s = (xx2 >= 0 && xx2 < HW) ? s : 0.f;
                }
                s += __shfl_xor(s, 1, 64);
                s += __shfl_xor(s, 2, 64);
                s += __shfl_xor(s, 4, 64);
                s += __shfl_xor(s, 8, 64);
                if (cs == 0 && lc2 < 26) dgw[a * DGS + lc2] = s;
            }
        }
    }
    __syncthreads();

    // Phase C: long wave blends its creg from the corner grid
    if (isLong) {
        float fy = (float)y + oy, fx = (float)x + ox;
        float fy0 = floorf(fy), fx0 = floorf(fx);
        float wy = fy - fy0, wx = fx - fx0;
        const float* dgw = dgw_s[r];
        float w00 = (1.f - wy) * (1.f - wx), w01 = (1.f - wy) * wx;
        float w10 = wy * (1.f - wx), w11 = wy * wx;
#pragma unroll
        for (int jj = 0; jj < 10; ++jj) {
            int t = lane + 64 * jj;
            if (t < NTAP) {
                int a = t / PP, bcol = t % PP;
                creg[jj] = w00 * dgw[a * DGS + bcol] + w01 * dgw[a * DGS + bcol + 1] +
                           w10 * dgw[(a + 1) * DGS + bcol] + w11 * dgw[(a + 1) * DGS + bcol + 1];
            }
        }
    }

    // top-K via f64-packed keys, two winners per butterfly, gather fused,
    // per-ref max m_r (barrier-free).
    double key[10];
#pragma unroll
    for (int jj = 0; jj < 10; ++jj) {
        float v = creg[jj] + 0.0f;              // normalize -0 -> +0
        unsigned u = __float_as_uint(v);
        u = (u & 0x80000000u) ? ~u : (u | 0x80000000u);
        int t = lane + 64 * jj;
        key[jj] = (double)u * 1024.0 + (double)(1023 - t);
    }

    int c = lane & 31, h = lane >> 5;
    const float* qb = qrT + (size_t)r * NPIX * CQ;
    float ssum = 0.f, acc = 0.f, m = 0.f;

    for (int k2 = 0; k2 < KTOP / 2; ++k2) {
        // per-lane top-2 (a >= b)
        double a = key[0], b = -1.0;            // all live keys > 0
#pragma unroll
        for (int jj = 1; jj < 10; ++jj) {
            double kk = key[jj];
            double na = fmax(a, kk);
            b = fmax(b, fmin(a, kk));
            a = na;
        }
        // butterfly top-2 merge across 64 lanes
#pragma unroll
        for (int s = 32; s; s >>= 1) {
            double pa = __shfl_xor(a, s, 64);
            double pb = __shfl_xor(b, s, 64);
            double na = fmax(a, pa);
            b = fmax(fmin(a, pa), fmax(b, pb));
            a = na;
        }
        // decode both winners on all lanes
        double qa = floor(a * (1.0 / 1024.0));
        double qb2 = floor(b * (1.0 / 1024.0));
        unsigned ua = (unsigned)qa, ub = (unsigned)qb2;
        unsigned ba = (ua & 0x80000000u) ? (ua ^ 0x80000000u) : ~ua;
        unsigned bb = (ub & 0x80000000u) ? (ub ^ 0x80000000u) : ~ub;
        float va = __uint_as_float(ba), vb = __uint_as_float(bb);
        int ta = 1023 - (int)(a - qa * 1024.0);
        int tb = 1023 - (int)(b - qb2 * 1024.0);

        if (k2 == 0) {
            m = va;                             // per-ref max
            if (lane == 0) mL[r] = va;
        }
        float vv = h ? vb : va;
        int tt = h ? tb : ta;
        float e = __expf(vv - m);
        ssum += e;
        acc += e * gather_color(qb, c, y, x, tt, isLong, oy, ox);

        // clear both winners (keys unique -> exact)
#pragma unroll
        for (int jj = 0; jj < 10; ++jj) {
            double kk = key[jj];
            key[jj] = (kk == a || kk == b) ? 0.0 : kk;
        }
    }
    accL[wid][lane] = acc;
    ssmL[wid][lane] = ssum;
    __syncthreads();

    if (wid == 0) {
        float M = mL[0];
        for (int w = 1; w < nref; ++w) M = fmaxf(M, mL[w]);
        float ta2 = 0.f, ts = 0.f;
        for (int w = 0; w < nref; ++w) {
            float sc = __expf(mL[w] - M);
            ta2 += accL[w][lane] * sc;
            ts += ssmL[w][lane] * sc;
        }
        ta2 += __shfl_xor(ta2, 32, 64);
        ts += __shfl_xor(ts, 32, 64);
        if (h == 0) out[(size_t)c * NPIX + p] = ta2 / ts;
    }
}

// ---- launcher --------------------------------------------------------------
extern "C" void kernel_launch(void* const* d_in, const int* in_sizes, int n_in,
                              void* d_out, int out_size, void* d_ws, size_t ws_size,
                              hipStream_t stream) {
    const float* fr = (const float*)d_in[0];   // (nref,1,64,48,48)
    const float* ft = (const float*)d_in[1];   // (1,64,48,48)
    const float* q  = (const float*)d_in[2];   // (nref,1,32,192,192)
    const void* refIdx = d_in[3];
    const void* curInd = d_in[4];
    int nref = in_sizes[0] / (CF * NPIX);

    float* ws  = (float*)d_ws;
    float* ftT = ws;
    float* frT = ftT + (size_t)NPIX * CF;
    float* qrT = frT + (size_t)nref * NPIX * CF;
    float* corr = qrT + (size_t)nref * NPIX * CQ;

    int total = NPIX * CF + nref * NPIX * CF + nref * NPIX * CQ;
    prep_kernel<<<(total + 255) / 256, 256, 0, stream>>>(fr, ft, q, nref, ftT, frT, qrT);
    corr_band<<<dim3(HW * 9, nref), 256, 0, stream>>>(ftT, frT, refIdx, curInd, corr);
    corr_fuse<<<dim3(NPIX), 64 * nref, 0, stream>>>(ftT, frT, qrT, corr, refIdx, curInd,
                                                    nref, (float*)d_out);
}

// Round 15
// 102.909 us; speedup vs baseline: 1.1264x; 1.1264x over previous
//
#include <hip/hip_runtime.h>
#include <math.h>

#define HW 48
#define NPIX 2304          // 48*48
#define CF 64
#define CQ 32
#define RAD 12
#define PP 25
#define NTAP 625           // 25*25
#define KTOP 20
#define DILINT 16
#define QW 192
#define CSTRIDE 640        // corr row stride (625 padded)
#define NPB 6              // pixels per corr_band block
#define NC 30              // staged columns per row (j+dx: 0..29)
#define LROW 68            // LDS col stride in floats
#define DGS 28             // dgrid row stride

// ---- helpers ---------------------------------------------------------------

// ref_index may arrive as int32 or int64; detect via first 8 bytes.
__device__ inline int read_ref_index(const void* rip, int r) {
    const long long* p64 = (const long long*)rip;
    long long v0 = p64[0];
    if (v0 >= 0 && v0 < 1000000) return (int)p64[r];   // plausible int64 layout
    return ((const int*)rip)[r];                       // int32 layout
}

__device__ inline int get_dil(const void* refIdx, const void* curInd, int r,
                              bool* isLong) {
    int cur = ((const int*)curInd)[0];
    int gap = cur - read_ref_index(refIdx, r);
    *isLong = gap > DILINT;
    return *isLong ? min(4, gap / DILINT + 1) : 1;
}

// bilinear (long) / integer (short) color gather for tap id at pixel (y,x)
__device__ inline float gather_color(const float* __restrict__ qb, int c,
                                     int y, int x, int id, bool isLong,
                                     float oy, float ox) {
    int dr = id / PP - RAD, dc = id % PP - RAD;
    float img = 0.f;
    if (isLong) {
        float py = (float)y + oy + (float)dr;
        float px = (float)x + ox + (float)dc;
        float fy0 = floorf(py), fx0 = floorf(px);
        int y0 = (int)fy0, x0 = (int)fx0;
        float wy = py - fy0, wx = px - fx0;
        float w00 = (1.f - wy) * (1.f - wx), w01 = (1.f - wy) * wx;
        float w10 = wy * (1.f - wx), w11 = wy * wx;
        if (y0 >= 0 && y0 < HW && x0 >= 0 && x0 < HW)
            img += w00 * qb[(y0 * HW + x0) * CQ + c];
        if (y0 >= 0 && y0 < HW && x0 + 1 >= 0 && x0 + 1 < HW)
            img += w01 * qb[(y0 * HW + x0 + 1) * CQ + c];
        if (y0 + 1 >= 0 && y0 + 1 < HW && x0 >= 0 && x0 < HW)
            img += w10 * qb[((y0 + 1) * HW + x0) * CQ + c];
        if (y0 + 1 >= 0 && y0 + 1 < HW && x0 + 1 >= 0 && x0 + 1 < HW)
            img += w11 * qb[((y0 + 1) * HW + x0 + 1) * CQ + c];
    } else {
        int yy = y + dr, xx = x + dc;
        if (yy >= 0 && yy < HW && xx >= 0 && xx < HW)
            img = qb[(yy * HW + xx) * CQ + c];
    }
    return img;
}

// ---- kernel 1: layout prep (R11 proven form) -------------------------------
__global__ void prep_kernel(const float* __restrict__ fr,
                            const float* __restrict__ ft,
                            const float* __restrict__ q, int nref,
                            float* __restrict__ ftT,
                            float* __restrict__ frT,
                            float* __restrict__ qrT) {
    int i = blockIdx.x * blockDim.x + threadIdx.x;
    int tft = NPIX * CF;
    int tfr = nref * NPIX * CF;
    int tqr = nref * NPIX * CQ;
    if (i < tft) {
        int p = i >> 6, c = i & 63;
        ftT[i] = ft[c * NPIX + p];
    } else if (i < tft + tfr) {
        int j = i - tft;
        int rr = j / (NPIX * CF);
        int rem = j % (NPIX * CF);
        int p = rem >> 6, c = rem & 63;
        frT[j] = fr[((size_t)rr * CF + c) * NPIX + p];
    } else if (i < tft + tfr + tqr) {
        int j = i - tft - tfr;
        int rr = j / (NPIX * CQ);
        int rem = j % (NPIX * CQ);
        int p = rem >> 5, c = rem & 31;
        int y = p / HW, x = p % HW;
        qrT[j] = q[(((size_t)rr * CQ + c) * QW + 4 * y) * QW + 4 * x];
    }
}

// ---- kernel 2a: integer-tap correlation, row-staged (R5/R11 proven form) ---
__global__ __launch_bounds__(256) void corr_band(
    const float* __restrict__ ftT, const float* __restrict__ frT,
    const void* __restrict__ refIdx, const void* __restrict__ curInd,
    float* __restrict__ corr) {
    __shared__ float lrow[NC * LROW];

    int tid = threadIdx.x;
    int bx = blockIdx.x % 9;
    int y = blockIdx.x / 9;
    int r = blockIdx.y;

    bool isLong;
    int dil = get_dil(refIdx, curInd, r, &isLong);
    int nb = (dil == 3) ? 9 : 8;
    if (bx >= nb) return;

    int m = bx % dil, grp = bx / dil;
    int npr = HW / dil;

    int T = tid;
    bool active = T < NPB * PP;
    int j = active ? T / PP : 0;
    int dxi = active ? T - PP * j : 0;
    int xoff = grp * NPB + j;
    bool pvalid = active && (xoff < npr);
    int xj = m + dil * xoff;
    int pj = pvalid ? (y * HW + xj) : 0;
    int lc = j + dxi;

    float4 fq[16];
    const float4* fp = (const float4*)(ftT + (size_t)pj * CF);
#pragma unroll
    for (int i = 0; i < 16; ++i) fq[i] = fp[i];

    const float* frb = frT + (size_t)r * NPIX * CF;
    float* outb = corr + ((size_t)r * NPIX + pj) * CSTRIDE + dxi;
    int gc0 = m + dil * (grp * NPB - RAD);

    for (int dy = 0; dy < PP; ++dy) {
        int yy = y + dil * (dy - RAD);
        if (yy < 0 || yy >= HW) {
            if (pvalid) outb[dy * PP] = 0.f;
            continue;
        }
        for (int k = tid; k < NC * 16; k += 256) {
            int col = k >> 4, sub = k & 15;
            int gc = gc0 + dil * col;
            float4 v = {0.f, 0.f, 0.f, 0.f};
            if (gc >= 0 && gc < HW)
                v = *(const float4*)(frb + ((size_t)yy * HW + gc) * CF + sub * 4);
            *(float4*)(lrow + col * LROW + sub * 4) = v;
        }
        __syncthreads();
        if (pvalid) {
            const float* bp = lrow + lc * LROW;
            float s = 0.f;
#pragma unroll
            for (int i = 0; i < 16; ++i) {
                float4 b = *(const float4*)(bp + 4 * i);
                s += fq[i].x * b.x + fq[i].y * b.y + fq[i].z * b.z + fq[i].w * b.w;
            }
            outb[dy * PP] = s;
        }
        __syncthreads();
    }
}

// ---- kernel 2b: fused per-pixel block, one wave per ref --------------------
// Phase B flattened: 676 corner-dot tasks spread over 12 coop-16 groups in
// 57 rounds (was 78 with 27% idle-group waste).
__global__ __launch_bounds__(192) void corr_fuse(
    const float* __restrict__ ftT, const float* __restrict__ frT,
    const float* __restrict__ qrT, const float* __restrict__ corr,
    const void* __restrict__ refIdx, const void* __restrict__ curInd,
    int nref, float* __restrict__ out) {
    __shared__ float dgw_s[3][27 * DGS];
    __shared__ float accL[3][64];
    __shared__ float ssmL[3][64];
    __shared__ float offL[3][2];
    __shared__ float mL[3];

    int tid = threadIdx.x;
    int wid = tid >> 6, lane = tid & 63;
    int p = blockIdx.x;
    int y = p / HW, x = p % HW;
    int r = wid;                      // one wave per ref (block = 64*nref)

    bool isLong;
    int dil = get_dil(refIdx, curInd, r, &isLong);
    float oy = 0.f, ox = 0.f;

    const float* cb = corr + ((size_t)r * NPIX + p) * CSTRIDE;
    float creg[10];
#pragma unroll
    for (int jj = 0; jj < 10; ++jj) {
        int t = lane + 64 * jj;
        creg[jj] = (t < NTAP) ? cb[t] : -INFINITY;
    }

    if (isLong) {
        // softmax over 625 taps -> expected offsets (exact expf: feeds top-k)
        float M = -INFINITY;
#pragma unroll
        for (int jj = 0; jj < 10; ++jj) M = fmaxf(M, creg[jj]);
#pragma unroll
        for (int s = 32; s; s >>= 1) M = fmaxf(M, __shfl_xor(M, s, 64));
        float s0 = 0.f, sy = 0.f, sx = 0.f;
#pragma unroll
        for (int jj = 0; jj < 10; ++jj) {
            int t = lane + 64 * jj;
            if (t < NTAP) {
                float e = expf(creg[jj] - M);
                int dy = t / PP - RAD, dx = t % PP - RAD;
                s0 += e; sy += e * (float)dy; sx += e * (float)dx;
            }
        }
#pragma unroll
        for (int s = 32; s; s >>= 1) {
            s0 += __shfl_xor(s0, s, 64);
            sy += __shfl_xor(sy, s, 64);
            sx += __shfl_xor(sx, s, 64);
        }
        oy = sy / s0 * (float)dil;
        ox = sx / s0 * (float)dil;
        if (lane == 0) { offL[r][0] = oy; offL[r][1] = ox; }
    }
    __syncthreads();

    // Phase B: cooperative corner grids, flat task index, all groups busy
    int cs = tid & 15;
    int g2 = tid >> 4;                          // 0..11 coop-16 groups
    float4 fqc = ((const float4*)(ftT + (size_t)p * CF))[cs];
    for (int rr = 0; rr < nref; ++rr) {
        bool rrLong;
        get_dil(refIdx, curInd, rr, &rrLong);
        if (!rrLong) continue;                  // block-uniform
        float roy = offL[rr][0], rox = offL[rr][1];
        float fy = (float)y + roy, fx = (float)x + rox;
        int iy0 = (int)floorf(fy), ix0 = (int)floorf(fx);

        const float* frb = frT + (size_t)rr * NPIX * CF;
        float* dgw = dgw_s[rr];
        int colbase = ix0 - RAD;
        int rowbase = iy0 - RAD;
        for (int rnd = 0; rnd < 57; ++rnd) {
            int idx = 12 * rnd + g2;            // task 0..683, use <676
            int a = idx / 26;
            int lc2 = idx - 26 * a;
            bool valid = idx < 676;
            int yy = rowbase + a;
            int xx2 = colbase + lc2;
            int ys = min(max(yy, 0), HW - 1);
            int xs = min(max(xx2, 0), HW - 1);
            bool ok = valid && (yy >= 0) && (yy < HW) && (xx2 >= 0) && (xx2 < HW);
            // unconditional clamped load (always in-bounds), mask result
            float4 b = *(const float4*)(frb + ((size_t)ys * HW + xs) * CF + 4 * cs);
            float t0 = fqc.x * b.x + fqc.y * b.y + fqc.z * b.z + fqc.w * b.w;
            float s = ok ? t0 : 0.f;
            s += __shfl_xor(s, 1, 64);
            s += __shfl_xor(s, 2, 64);
            s += __shfl_xor(s, 4, 64);
            s += __shfl_xor(s, 8, 64);
            if (cs == 0 && valid) dgw[a * DGS + lc2] = s;
        }
    }
    __syncthreads();

    // Phase C: long wave blends its creg from the corner grid
    if (isLong) {
        float fy = (float)y + oy, fx = (float)x + ox;
        float fy0 = floorf(fy), fx0 = floorf(fx);
        float wy = fy - fy0, wx = fx - fx0;
        const float* dgw = dgw_s[r];
        float w00 = (1.f - wy) * (1.f - wx), w01 = (1.f - wy) * wx;
        float w10 = wy * (1.f - wx), w11 = wy * wx;
#pragma unroll
        for (int jj = 0; jj < 10; ++jj) {
            int t = lane + 64 * jj;
            if (t < NTAP) {
                int a = t / PP, bcol = t % PP;
                creg[jj] = w00 * dgw[a * DGS + bcol] + w01 * dgw[a * DGS + bcol + 1] +
                           w10 * dgw[(a + 1) * DGS + bcol] + w11 * dgw[(a + 1) * DGS + bcol + 1];
            }
        }
    }

    // top-K via f64-packed keys, two winners per butterfly, gather fused,
    // per-ref max m_r (barrier-free).
    double key[10];
#pragma unroll
    for (int jj = 0; jj < 10; ++jj) {
        float v = creg[jj] + 0.0f;              // normalize -0 -> +0
        unsigned u = __float_as_uint(v);
        u = (u & 0x80000000u) ? ~u : (u | 0x80000000u);
        int t = lane + 64 * jj;
        key[jj] = (double)u * 1024.0 + (double)(1023 - t);
    }

    int c = lane & 31, h = lane >> 5;
    const float* qb = qrT + (size_t)r * NPIX * CQ;
    float ssum = 0.f, acc = 0.f, m = 0.f;

    for (int k2 = 0; k2 < KTOP / 2; ++k2) {
        // per-lane top-2 (a >= b)
        double a = key[0], b = -1.0;            // all live keys > 0
#pragma unroll
        for (int jj = 1; jj < 10; ++jj) {
            double kk = key[jj];
            double na = fmax(a, kk);
            b = fmax(b, fmin(a, kk));
            a = na;
        }
        // butterfly top-2 merge across 64 lanes
#pragma unroll
        for (int s = 32; s; s >>= 1) {
            double pa = __shfl_xor(a, s, 64);
            double pb = __shfl_xor(b, s, 64);
            double na = fmax(a, pa);
            b = fmax(fmin(a, pa), fmax(b, pb));
            a = na;
        }
        // decode both winners on all lanes
        double qa = floor(a * (1.0 / 1024.0));
        double qb2 = floor(b * (1.0 / 1024.0));
        unsigned ua = (unsigned)qa, ub = (unsigned)qb2;
        unsigned ba = (ua & 0x80000000u) ? (ua ^ 0x80000000u) : ~ua;
        unsigned bb = (ub & 0x80000000u) ? (ub ^ 0x80000000u) : ~ub;
        float va = __uint_as_float(ba), vb = __uint_as_float(bb);
        int ta = 1023 - (int)(a - qa * 1024.0);
        int tb = 1023 - (int)(b - qb2 * 1024.0);

        if (k2 == 0) {
            m = va;                             // per-ref max
            if (lane == 0) mL[r] = va;
        }
        float vv = h ? vb : va;
        int tt = h ? tb : ta;
        float e = __expf(vv - m);
        ssum += e;
        acc += e * gather_color(qb, c, y, x, tt, isLong, oy, ox);

        // clear both winners (keys unique -> exact)
#pragma unroll
        for (int jj = 0; jj < 10; ++jj) {
            double kk = key[jj];
            key[jj] = (kk == a || kk == b) ? 0.0 : kk;
        }
    }
    accL[wid][lane] = acc;
    ssmL[wid][lane] = ssum;
    __syncthreads();

    if (wid == 0) {
        float M = mL[0];
        for (int w = 1; w < nref; ++w) M = fmaxf(M, mL[w]);
        float ta2 = 0.f, ts = 0.f;
        for (int w = 0; w < nref; ++w) {
            float sc = __expf(mL[w] - M);
            ta2 += accL[w][lane] * sc;
            ts += ssmL[w][lane] * sc;
        }
        ta2 += __shfl_xor(ta2, 32, 64);
        ts += __shfl_xor(ts, 32, 64);
        if (h == 0) out[(size_t)c * NPIX + p] = ta2 / ts;
    }
}

// ---- launcher --------------------------------------------------------------
extern "C" void kernel_launch(void* const* d_in, const int* in_sizes, int n_in,
                              void* d_out, int out_size, void* d_ws, size_t ws_size,
                              hipStream_t stream) {
    const float* fr = (const float*)d_in[0];   // (nref,1,64,48,48)
    const float* ft = (const float*)d_in[1];   // (1,64,48,48)
    const float* q  = (const float*)d_in[2];   // (nref,1,32,192,192)
    const void* refIdx = d_in[3];
    const void* curInd = d_in[4];
    int nref = in_sizes[0] / (CF * NPIX);

    float* ws  = (float*)d_ws;
    float* ftT = ws;
    float* frT = ftT + (size_t)NPIX * CF;
    float* qrT = frT + (size_t)nref * NPIX * CF;
    float* corr = qrT + (size_t)nref * NPIX * CQ;

    int total = NPIX * CF + nref * NPIX * CF + nref * NPIX * CQ;
    prep_kernel<<<(total + 255) / 256, 256, 0, stream>>>(fr, ft, q, nref, ftT, frT, qrT);
    corr_band<<<dim3(HW * 9, nref), 256, 0, stream>>>(ftT, frT, refIdx, curInd, corr);
    corr_fuse<<<dim3(NPIX), 64 * nref, 0, stream>>>(ftT, frT, qrT, corr, refIdx, curInd,
                                                    nref, (float*)d_out);
}